// Round 2
// baseline (302.350 us; speedup 1.0000x reference)
//
#include <hip/hip_runtime.h>
#include <stdint.h>

#define B_ 8
#define C_ 256
#define N_ 4096
#define CQK 32

typedef __attribute__((ext_vector_type(8))) _Float16 f16x8;
typedef __attribute__((ext_vector_type(4))) float f32x4;

__device__ __forceinline__ unsigned short f2bf_rne(float f) {
  unsigned u = __builtin_bit_cast(unsigned, f);
  u += 0x7FFFu + ((u >> 16) & 1u);
  return (unsigned short)(u >> 16);
}

// ---------------------------------------------------------------------------
// Kernel 1: transpose x [b][c][n] fp32 -> xT [b][n][c] fp16 (c contiguous).
// Tile: 64 c x 128 n per block. 1024 blocks, 256 thr.
// ---------------------------------------------------------------------------
__global__ __launch_bounds__(256) void xpose_kernel(
    const float* __restrict__ x, _Float16* __restrict__ xT)
{
  __shared__ float xs[64 * 129];
  const int t  = threadIdx.x;
  const int blk = blockIdx.x;
  const int nt = blk & 31;          // n-tile (128 px)
  const int ct = (blk >> 5) & 3;    // c-tile (64 ch)
  const int b  = blk >> 7;
  const int c0 = ct * 64, n0 = nt * 128;

  #pragma unroll
  for (int p = 0; p < 8; ++p) {
    int cc = p * 8 + (t >> 5);
    int nn = (t & 31) * 4;
    float4 v = *(const float4*)(x + ((size_t)(b * C_ + c0 + cc)) * N_ + n0 + nn);
    xs[cc * 129 + nn]     = v.x;
    xs[cc * 129 + nn + 1] = v.y;
    xs[cc * 129 + nn + 2] = v.z;
    xs[cc * 129 + nn + 3] = v.w;
  }
  __syncthreads();
  #pragma unroll
  for (int p = 0; p < 4; ++p) {
    int id = p * 256 + t;
    int cchunk = id & 7, n = id >> 3;   // n in [0,128)
    _Float16 h[8];
    #pragma unroll
    for (int j = 0; j < 8; ++j) h[j] = (_Float16)xs[(cchunk * 8 + j) * 129 + n];
    *(f16x8*)(xT + ((size_t)(b * N_) + n0 + n) * C_ + c0 + cchunk * 8) = *(f16x8*)h;
  }
}

// ---------------------------------------------------------------------------
// Kernel 2: convert weights to fp16, concatenated Wcat[320][256]:
// rows 0-31 = wq, 32-63 = wk, 64-319 = wv.
// ---------------------------------------------------------------------------
__global__ __launch_bounds__(256) void wconv_kernel(
    const float* __restrict__ wq, const float* __restrict__ wk,
    const float* __restrict__ wv, _Float16* __restrict__ wf)
{
  int idx = blockIdx.x * 256 + threadIdx.x;   // 20480 threads x 4 elems
  int e = idx * 4;
  int o = e >> 8, c = e & 255;
  const float* src;
  if (o < 32)      src = wq + o * 256 + c;
  else if (o < 64) src = wk + (o - 32) * 256 + c;
  else             src = wv + (o - 64) * 256 + c;
  float4 v = *(const float4*)src;
  _Float16 h[4] = {(_Float16)v.x, (_Float16)v.y, (_Float16)v.z, (_Float16)v.w};
  *(uint2*)(wf + e) = *(uint2*)h;
}

// ---------------------------------------------------------------------------
// Kernel 3: projection GEMM (fp16 MFMA): D[o][n] = Wcat[o][:] . xT[n][:]
// Block = 64 o x 128 n, 256 thr (4 waves: wave = 32 o x 64 n).
// otile 0 -> q/k rows (store transposed [n][c']); otiles 1-4 -> v [c][n].
// q rows are PRE-SCALED by log2(e) so attention can use exp2 directly.
// ---------------------------------------------------------------------------
__global__ __launch_bounds__(256, 4) void proj_gemm_kernel(
    const _Float16* __restrict__ xT, const _Float16* __restrict__ wf,
    const float* __restrict__ bq, const float* __restrict__ bk,
    const float* __restrict__ bv,
    _Float16* __restrict__ qf, _Float16* __restrict__ kf,
    _Float16* __restrict__ vout)
{
  const int t = threadIdx.x, lane = t & 63;
  const int w = t >> 6;
  const int l15 = lane & 15, q4 = lane >> 4;
  const int blk = blockIdx.x;
  const int otile = blk % 5;          // 0 = q/k, 1..4 = v
  const int nt = blk / 5;             // 256 n-tiles (8 b x 32)
  const int b  = nt >> 5;
  const int n0 = (nt & 31) * 128;
  const int o0w = (w & 1) * 32;       // wave o-offset within the 64-row tile
  const int n0w = (w >> 1) * 64;      // wave n-offset within the 128-px tile

  f32x4 acc[2][4];
  const f32x4 zf = {0.f, 0.f, 0.f, 0.f};
  #pragma unroll
  for (int a = 0; a < 2; ++a)
    #pragma unroll
    for (int bb = 0; bb < 4; ++bb) acc[a][bb] = zf;

  const _Float16* wbase = wf + (size_t)(otile * 64 + o0w) * 256;
  const _Float16* xbase = xT + ((size_t)(b * N_) + n0 + n0w) * C_;

  #pragma unroll
  for (int kc = 0; kc < 8; ++kc) {
    f16x8 af[2], bfr[4];
    #pragma unroll
    for (int ob = 0; ob < 2; ++ob)
      af[ob] = *(const f16x8*)(wbase + (ob * 16 + l15) * 256 + kc * 32 + q4 * 8);
    #pragma unroll
    for (int nb = 0; nb < 4; ++nb)
      bfr[nb] = *(const f16x8*)(xbase + (nb * 16 + l15) * 256 + kc * 32 + q4 * 8);
    #pragma unroll
    for (int ob = 0; ob < 2; ++ob)
      #pragma unroll
      for (int nb = 0; nb < 4; ++nb)
        acc[ob][nb] = __builtin_amdgcn_mfma_f32_16x16x32_f16(af[ob], bfr[nb], acc[ob][nb], 0, 0, 0);
  }

  if (otile == 0) {
    _Float16* dst = (o0w == 0) ? qf : kf;
    const float* bias = (o0w == 0) ? bq : bk;
    const float qsc = (o0w == 0) ? 1.4426950408889634f : 1.0f;  // log2(e) for q
    #pragma unroll
    for (int ob = 0; ob < 2; ++ob) {
      float4 b4 = *(const float4*)(bias + ob * 16 + q4 * 4);
      #pragma unroll
      for (int nb = 0; nb < 4; ++nb) {
        int pixel = n0 + n0w + nb * 16 + l15;
        _Float16 h[4];
        h[0] = (_Float16)((acc[ob][nb][0] + b4.x) * qsc);
        h[1] = (_Float16)((acc[ob][nb][1] + b4.y) * qsc);
        h[2] = (_Float16)((acc[ob][nb][2] + b4.z) * qsc);
        h[3] = (_Float16)((acc[ob][nb][3] + b4.w) * qsc);
        *(uint2*)(dst + ((size_t)(b * N_) + pixel) * CQK + ob * 16 + q4 * 4) = *(uint2*)h;
      }
    }
  } else {
    int cbase = (otile - 1) * 64 + o0w;
    #pragma unroll
    for (int ob = 0; ob < 2; ++ob) {
      float4 b4 = *(const float4*)(bv + cbase + ob * 16 + q4 * 4);
      #pragma unroll
      for (int nb = 0; nb < 4; ++nb) {
        int pixel = n0 + n0w + nb * 16 + l15;
        #pragma unroll
        for (int r = 0; r < 4; ++r) {
          int c = cbase + ob * 16 + q4 * 4 + r;
          float bval = (r == 0) ? b4.x : (r == 1) ? b4.y : (r == 2) ? b4.z : b4.w;
          vout[((size_t)(b * C_) + c) * N_ + pixel] = (_Float16)(acc[ob][nb][r] + bval);
        }
      }
    }
  }
}

// ---------------------------------------------------------------------------
// Kernel 4: fused flash attention + residual -> yout (bf16).
// 256 thr (4 waves), M=64 queries/block, NT=64 keys/iter, grid 512 (2/CU).
// Each wave owns 16 FULL query rows in the S phase (4 MFMAs over all 64 j),
// so softmax max/sum reduce fully in-wave (2 shfl_xor) -- no pmax/psum LDS.
// ONE barrier per iteration: P (and alpha/flags) are double-buffered in LDS.
//   write P(j) -> bar(j) -> read P(j); next write of the same buffer is at
//   iter j+2, behind bar(j+1); last read of it was PV(j), before bar(j+1).
// K for iter j+1 is register-prefetched before softmax(j) (in flight across
// the barrier); V(j) is issued at iter top and consumed after the barrier.
// Defer-max (THR=8 in log2 domain): P <= 2^8, safe in fp16; rescale is rare.
// PV: wave = 64-channel strip, 32 MFMAs/iter -> 36 MFMAs per barrier.
// NOTE: __ballot MUST be evaluated at full-wave scope (round-1 bug: it was
// inside `if (lane==0)`, so it only saw row 0's update -> missed rescales).
// ---------------------------------------------------------------------------
#define ATTN_BODY(JT, KC, KN) do { \
  const int buf_ = (JT) & 1; \
  /* V loads for this iter (consumed after the barrier in PV) */ \
  f16x8 vv_[8]; \
  _Pragma("unroll") \
  for (int ks = 0; ks < 2; ++ks) { \
    vv_[ks * 4 + 0] = *(const f16x8*)(vp0 + ks * 32); \
    vv_[ks * 4 + 1] = *(const f16x8*)(vp1 + ks * 32); \
    vv_[ks * 4 + 2] = *(const f16x8*)(vp2 + ks * 32); \
    vv_[ks * 4 + 3] = *(const f16x8*)(vp3 + ks * 32); \
  } \
  vp0 += 64; vp1 += 64; vp2 += 64; vp3 += 64; \
  /* prefetch next K tile into KN (wraps at the end; regs just unused) */ \
  { const _Float16* knp_ = kbase + (size_t)((((JT) + 1) & 63) * 64) * CQK; \
    _Pragma("unroll") \
    for (int jb = 0; jb < 4; ++jb) KN[jb] = *(const f16x8*)(knp_ + jb * 16 * CQK); } \
  /* S' = K x Q : 64 j x 16 i, j = jb*16 + q4*4 + r, i = w*16 + l15 */ \
  f32x4 sv_[4]; \
  _Pragma("unroll") \
  for (int jb = 0; jb < 4; ++jb) \
    sv_[jb] = __builtin_amdgcn_mfma_f32_16x16x32_f16(KC[jb], qfr, zf, 0, 0, 0); \
  float lm_ = sv_[0][0]; \
  _Pragma("unroll") \
  for (int jb = 0; jb < 4; ++jb) \
    lm_ = fmaxf(lm_, fmaxf(fmaxf(sv_[jb][0], sv_[jb][1]), fmaxf(sv_[jb][2], sv_[jb][3]))); \
  lm_ = fmaxf(lm_, __shfl_xor(lm_, 16)); \
  lm_ = fmaxf(lm_, __shfl_xor(lm_, 32)); \
  bool upd_ = lm_ > mold + 8.0f; \
  unsigned long long bal_ = __ballot(upd_);            /* full-wave scope! */ \
  float alpha_ = upd_ ? exp2f(mold - lm_) : 1.0f; \
  if (upd_) mold = lm_; \
  float ts_ = 0.f; \
  float p_[4][4]; \
  _Pragma("unroll") \
  for (int jb = 0; jb < 4; ++jb) \
    _Pragma("unroll") \
    for (int r = 0; r < 4; ++r) { p_[jb][r] = exp2f(sv_[jb][r] - mold); ts_ += p_[jb][r]; } \
  ts_ += __shfl_xor(ts_, 16); \
  ts_ += __shfl_xor(ts_, 32); \
  lrun = lrun * alpha_ + ts_; \
  { char* pb_ = (char*)Plds + buf_ * 9216 + (w * 16 + l15) * 144 + q4 * 8; \
    _Pragma("unroll") \
    for (int jb = 0; jb < 4; ++jb) { \
      _Float16 h_[4] = {(_Float16)p_[jb][0], (_Float16)p_[jb][1], \
                        (_Float16)p_[jb][2], (_Float16)p_[jb][3]}; \
      *(uint2*)(pb_ + jb * 32) = *(uint2*)h_; } } \
  if (q4 == 0) alphal[buf_ * 64 + w * 16 + l15] = alpha_; \
  if (lane == 0) flagw[buf_ * 4 + w] = (bal_ != 0ull) ? 1 : 0; \
  __syncthreads(); \
  { int4 fl_ = *(const int4*)(flagw + buf_ * 4); \
    if (fl_.x | fl_.y | fl_.z | fl_.w) { \
      _Pragma("unroll") \
      for (int ib = 0; ib < 4; ++ib) { \
        float av_ = alphal[buf_ * 64 + ib * 16 + l15]; \
        _Pragma("unroll") \
        for (int cb = 0; cb < 4; ++cb) \
          _Pragma("unroll") \
          for (int r = 0; r < 4; ++r) acc[cb][ib][r] *= av_; } } } \
  __builtin_amdgcn_s_setprio(1); \
  _Pragma("unroll") \
  for (int ks = 0; ks < 2; ++ks) { \
    f16x8 pf_[4]; \
    _Pragma("unroll") \
    for (int ib = 0; ib < 4; ++ib) \
      pf_[ib] = *(const f16x8*)((char*)Plds + buf_ * 9216 + (ib * 16 + l15) * 144 + ks * 64 + q4 * 16); \
    _Pragma("unroll") \
    for (int cb = 0; cb < 4; ++cb) \
      _Pragma("unroll") \
      for (int ib = 0; ib < 4; ++ib) \
        acc[cb][ib] = __builtin_amdgcn_mfma_f32_16x16x32_f16(vv_[ks * 4 + cb], pf_[ib], acc[cb][ib], 0, 0, 0); \
  } \
  __builtin_amdgcn_s_setprio(0); \
} while (0)

__global__ __launch_bounds__(256, 2) void attn_kernel(
    const float* __restrict__ x, const float* __restrict__ gptr,
    const _Float16* __restrict__ qf, const _Float16* __restrict__ kf,
    const _Float16* __restrict__ vf, unsigned short* __restrict__ yout)
{
  __shared__ __align__(16) char smem[19232];
  _Float16* Plds  = (_Float16*)smem;             // [2][64 rows][144 B]
  float* alphal = (float*)(smem + 18432);        // [2][64]
  int*   flagw  = (int*)(smem + 18944);          // [2][4]
  float* lrowl  = (float*)(smem + 18976);        // [64]

  const int t = threadIdx.x, lane = t & 63;
  const int w = t >> 6;                           // 4 waves
  const int l15 = lane & 15, q4 = lane >> 4;
  const int b  = blockIdx.x & 7;                  // batch == XCD -> V L2-resident
  const int it = blockIdx.x >> 3;
  const int i0 = it * 64;
  const float gamma = gptr[0];

  // Q fragment: this wave's 16 rows (q pre-scaled by log2 e in proj kernel)
  const f16x8 qfr = *(const f16x8*)(qf + ((size_t)(b * N_) + i0 + w * 16 + l15) * CQK + q4 * 8);

  // per-lane K base: row j = l15 (+16*jb), k-slice q4*8
  const _Float16* kbase = kf + ((size_t)(b * N_) + l15) * CQK + q4 * 8;
  // per-lane V pointers (one per cb): c = w*64 + cb*16 + l15, col q4*8 (+ks*32)
  const _Float16* vp0 = vf + ((size_t)(b * C_) + w * 64 + l15) * N_ + q4 * 8;
  const _Float16* vp1 = vp0 + (size_t)16 * N_;
  const _Float16* vp2 = vp0 + (size_t)32 * N_;
  const _Float16* vp3 = vp0 + (size_t)48 * N_;

  f32x4 acc[4][4];   // [cb][ib]: c = w*64+cb*16+q4*4+r, i = ib*16+l15
  const f32x4 zf = {0.f, 0.f, 0.f, 0.f};
  #pragma unroll
  for (int a = 0; a < 4; ++a)
    #pragma unroll
    for (int bb = 0; bb < 4; ++bb) acc[a][bb] = zf;

  float mold = -1e30f, lrun = 0.f;

  f16x8 ka[4], kb[4];
  #pragma unroll
  for (int jb = 0; jb < 4; ++jb) ka[jb] = *(const f16x8*)(kbase + jb * 16 * CQK);

  #pragma unroll 1
  for (int jt = 0; jt < 64; jt += 2) {
    ATTN_BODY(jt, ka, kb);
    ATTN_BODY(jt + 1, kb, ka);
  }

  if (q4 == 0) lrowl[w * 16 + l15] = lrun;
  __syncthreads();
  #pragma unroll
  for (int ib = 0; ib < 4; ++ib) {
    float linv = 1.0f / lrowl[ib * 16 + l15];
    int i = i0 + ib * 16 + l15;
    #pragma unroll
    for (int cb = 0; cb < 4; ++cb) {
      #pragma unroll
      for (int r = 0; r < 4; ++r) {
        int c = w * 64 + cb * 16 + q4 * 4 + r;
        size_t off = ((size_t)(b * C_) + c) * N_ + i;
        float o = acc[cb][ib][r] * linv;
        yout[off] = f2bf_rne(fmaf(gamma, o, x[off]));
      }
    }
  }
}

// ---------------------------------------------------------------------------
// Kernel 5: BN statistics from bf16 yout; one block per channel.
// ---------------------------------------------------------------------------
__global__ __launch_bounds__(256) void bnstats_kernel(
    const unsigned short* __restrict__ y, float* __restrict__ meanw, float* __restrict__ rstdw)
{
  const int c = blockIdx.x;
  const int t = threadIdx.x;
  float s1 = 0.f, s2 = 0.f;
  for (int b = 0; b < B_; ++b) {
    const unsigned short* p = y + ((size_t)(b * C_ + c)) * N_;
    #pragma unroll
    for (int r = 0; r < 2; ++r) {
      uint4 u = *(const uint4*)(p + r * 2048 + t * 8);
      unsigned uu[4] = {u.x, u.y, u.z, u.w};
      #pragma unroll
      for (int k = 0; k < 4; ++k) {
        float a = __builtin_bit_cast(float, uu[k] << 16);
        float bb = __builtin_bit_cast(float, uu[k] & 0xFFFF0000u);
        s1 += a + bb;
        s2 += a * a + bb * bb;
      }
    }
  }
  __shared__ float r1[256], r2[256];
  r1[t] = s1; r2[t] = s2;
  __syncthreads();
  for (int s = 128; s > 0; s >>= 1) {
    if (t < s) { r1[t] += r1[t + s]; r2[t] += r2[t + s]; }
    __syncthreads();
  }
  if (t == 0) {
    float mean = r1[0] * (1.0f / 32768.0f);
    float var  = r2[0] * (1.0f / 32768.0f) - mean * mean;
    meanw[c] = mean;
    rstdw[c] = rsqrtf(var + 1e-5f);
  }
}

// ---------------------------------------------------------------------------
// Kernel 6: BN normalize + ReLU: bf16 yout -> fp32 d_out.
// ---------------------------------------------------------------------------
__global__ __launch_bounds__(256) void bnapply_kernel(
    const unsigned short* __restrict__ y, float* __restrict__ out,
    const float* __restrict__ meanw, const float* __restrict__ rstdw,
    const float* __restrict__ bnw, const float* __restrict__ bnb)
{
  size_t idx = (size_t)blockIdx.x * 256 + threadIdx.x;   // 1,048,576 threads
  size_t el = idx * 8;
  int c = (int)((el >> 12) & 255);
  float sc = bnw[c] * rstdw[c];
  float sh = fmaf(-meanw[c], sc, bnb[c]);
  uint4 u = *(const uint4*)(y + el);
  unsigned uu[4] = {u.x, u.y, u.z, u.w};
  float4 o0, o1;
  float v[8];
  #pragma unroll
  for (int k = 0; k < 4; ++k) {
    v[2 * k]     = __builtin_bit_cast(float, uu[k] << 16);
    v[2 * k + 1] = __builtin_bit_cast(float, uu[k] & 0xFFFF0000u);
  }
  o0.x = fmaxf(fmaf(v[0], sc, sh), 0.f);
  o0.y = fmaxf(fmaf(v[1], sc, sh), 0.f);
  o0.z = fmaxf(fmaf(v[2], sc, sh), 0.f);
  o0.w = fmaxf(fmaf(v[3], sc, sh), 0.f);
  o1.x = fmaxf(fmaf(v[4], sc, sh), 0.f);
  o1.y = fmaxf(fmaf(v[5], sc, sh), 0.f);
  o1.z = fmaxf(fmaf(v[6], sc, sh), 0.f);
  o1.w = fmaxf(fmaf(v[7], sc, sh), 0.f);
  *(float4*)(out + el) = o0;
  *(float4*)(out + el + 4) = o1;
}

extern "C" void kernel_launch(void* const* d_in, const int* in_sizes, int n_in,
                              void* d_out, int out_size, void* d_ws, size_t ws_size,
                              hipStream_t stream)
{
  const float* x   = (const float*)d_in[0];
  const float* wq  = (const float*)d_in[1];
  const float* bq  = (const float*)d_in[2];
  const float* wk  = (const float*)d_in[3];
  const float* bk  = (const float*)d_in[4];
  const float* wv  = (const float*)d_in[5];
  const float* bv  = (const float*)d_in[6];
  const float* gm  = (const float*)d_in[7];
  const float* bnw = (const float*)d_in[8];
  const float* bnb = (const float*)d_in[9];
  float* out = (float*)d_out;

  // d_out doubles as scratch for xT and v (both dead before bnapply writes):
  //   [0, 16.78 MB)   xT fp16 [b][n][c]
  //   [16.78, 33.55)  v  fp16 [b][c][n]
  _Float16* xT  = (_Float16*)d_out;
  _Float16* vfp = (_Float16*)((char*)d_out + (size_t)B_ * C_ * N_ * 2);

  // ws: q 2MB | k 2MB | yout bf16 16.78MB | wf 160KB | stats  (~22 MB total)
  char* ws = (char*)d_ws;
  _Float16* qf = (_Float16*)(ws);
  _Float16* kf = (_Float16*)(ws + ((size_t)2 << 20));
  unsigned short* yout = (unsigned short*)(ws + ((size_t)4 << 20));
  _Float16* wf = (_Float16*)(ws + ((size_t)21 << 20));
  float* meanw = (float*)(ws + ((size_t)22 << 20));
  float* rstdw = (float*)(ws + ((size_t)22 << 20) + 4096);

  hipLaunchKernelGGL(xpose_kernel, dim3(1024), dim3(256), 0, stream, x, xT);
  hipLaunchKernelGGL(wconv_kernel, dim3(80), dim3(256), 0, stream, wq, wk, wv, wf);
  hipLaunchKernelGGL(proj_gemm_kernel, dim3(1280), dim3(256), 0, stream,
                     xT, wf, bq, bk, bv, qf, kf, vfp);
  hipLaunchKernelGGL(attn_kernel, dim3(512), dim3(256), 0, stream,
                     x, gm, qf, kf, vfp, yout);
  hipLaunchKernelGGL(bnstats_kernel, dim3(256), dim3(256), 0, stream,
                     yout, meanw, rstdw);
  hipLaunchKernelGGL(bnapply_kernel, dim3(4096), dim3(256), 0, stream,
                     yout, out, meanw, rstdw, bnw, bnb);
}